// Round 16
// baseline (1108.770 us; speedup 1.0000x reference)
//
#include <hip/hip_runtime.h>
#include <math.h>

#define TT 256
#define HH 100
#define GG 400
#define BB 512

typedef float  f32x2  __attribute__((ext_vector_type(2)));
typedef float  f32x4  __attribute__((ext_vector_type(4)));
typedef short  bf16x8 __attribute__((ext_vector_type(8)));

// ---- DPP quad-perm helpers (4-lane groups; VALU pipe) ----------------------
#define DPP_ROT1 147   // dest l <- src (l-1)&3 : perm [3,0,1,2]
#define DPP_ROT2 78    // dest l <- src (l-2)&3 : perm [2,3,0,1]
#define DPP_ROT3 57    // dest l <- src (l-3)&3 : perm [1,2,3,0]
#define DPP_XOR1 177   // perm [1,0,3,2]
#define DPP_XOR2 78    // perm [2,3,0,1]
#define DPP_XOR3 27    // perm [3,2,1,0]

template<int CTRL>
__device__ __forceinline__ float dppf(float v) {
    int i = __float_as_int(v);
    int r = __builtin_amdgcn_update_dpp(i, i, CTRL, 0xf, 0xf, false);
    return __int_as_float(r);
}

// packed fp32 FMA: acc.lo += w.lo*h.lo; acc.hi += w.hi*h.hi (exact fp32)
#define PKFMA(acc, w, h) \
    asm("v_pk_fma_f32 %0, %1, %2, %0" : "+v"(acc) : "v"(w), "v"(h))

// raw transcendental ops (validated: absmax 6.1e-5 since R8)
__device__ __forceinline__ float fexp2(float x) {
    float r; asm("v_exp_f32 %0, %1" : "=v"(r) : "v"(x)); return r;
}
__device__ __forceinline__ float frcp(float x) {
    float r; asm("v_rcp_f32 %0, %1" : "=v"(r) : "v"(x)); return r;
}
#define LOG2E 1.44269504088896f

// bf16 round-to-nearest-even of fp32 (returns 16-bit pattern)
__device__ __forceinline__ unsigned bf16rne(float x) {
    unsigned b = __float_as_uint(x);
    return (b + 0x7FFFu + ((b >> 16) & 1u)) >> 16;
}

// LDS-drain-only barrier: keeps global loads/stores in flight
__device__ __forceinline__ void bar_lds() {
    asm volatile("s_waitcnt lgkmcnt(0)" ::: "memory");
    __builtin_amdgcn_s_barrier();
    asm volatile("" ::: "memory");
}

// ============================ recurrence kernel ==============================
// R8 structure + v_pk_fma_f32 inner loop (48 pk_fma + 4 fmac replaces 100
// fmac — the dominant instruction class, and the one paying the AGPR tax).
// 512 blocks x 448 threads, 1 batch row/block, 2 blocks/CU; lb(448,3).
// Thread (u=tid>>2, ty=tid&3): k-quarter [25ty,25ty+25) partials for gates
// {((ty+d)&3)*100+u}; DPP-rotate combine (R4-verified). h dbuf LDS [2][4][28].
template<int LK>
__global__ void __launch_bounds__(448, 3)
lstm_recur(const float* __restrict__ x,        // [B][T][2]   (LK==0)
           const float* __restrict__ pre,      // [T*B][400]  (LK>=1, bias folded)
           const float* __restrict__ Whh,      // [400][100]
           const float* __restrict__ Wih0,     // [400][2]    (LK==0)
           const float* __restrict__ bih,      // [400]       (LK==0)
           const float* __restrict__ bhh,      // [400]       (LK==0)
           const float* __restrict__ head_w,   // [100]
           const float* __restrict__ head_b,   // [1]
           float* __restrict__ hs,             // [B][T][100] (LK<2 out)
           float* __restrict__ out)            // [B]         (LK==2 out)
{
    __shared__ float hbuf[2][4][28];   // [buf][quarter][25 used + 3 pad]

    const int tid = threadIdx.x;
    const int b   = blockIdx.x;        // one batch row per block
    const int u   = tid >> 2, ty = tid & 3;
    const int g   = ty * HH + u;       // own gate row
    const bool on = (tid < GG);

    // Wp[d][p] = pair {W[2p], W[2p+1]} of Whh[((ty+d)&3)*100+u][25ty..25ty+24];
    // Wt[d] = element 24 (odd tail).
    f32x2 Wp[4][12];
    float Wt[4];
    float w0a = 0.f, w0b = 0.f, bias = 0.f;
    if (on) {
        #pragma unroll
        for (int d = 0; d < 4; ++d) {
            const float* wrow = Whh + (((ty + d) & 3) * HH + u) * HH + 25 * ty;
            #pragma unroll
            for (int p = 0; p < 12; ++p)
                Wp[d][p] = (f32x2){wrow[2*p], wrow[2*p+1]};
            Wt[d] = wrow[24];
        }
        if (LK == 0) {
            w0a = Wih0[2 * g]; w0b = Wih0[2 * g + 1];
            bias = bih[g] + bhh[g];
        }
    }
    if (tid < 224) (&hbuf[0][0][0])[tid] = 0.f;   // zero both bufs incl. pads
    float c = 0.f;                                // ty==0 lanes own unit u's cell
    const int q_w = u / 25, i_w = u % 25;         // writer position
    __syncthreads();

    // prefetch t=0 input
    float p0 = 0.f;
    float2 xa = {0.f, 0.f};
    if (on) {
        if (LK == 0) xa = *(const float2*)(x + (size_t)b * TT * 2);
        else         p0 = pre[((size_t)0 * BB + b) * GG + g];
    }

    for (int t = 0; t < TT; ++t) {
        const int cur = t & 1, nxt = cur ^ 1;
        if (on) {
            float ext;
            if (LK == 0) ext = bias + w0a * xa.x + w0b * xa.y;
            else         ext = p0;

            // prefetch t+1 (stays in flight across the raw barrier)
            const int tn = (t + 1 < TT) ? t + 1 : t;
            if (LK == 0) xa = *(const float2*)(x + ((size_t)b * TT + tn) * 2);
            else         p0 = pre[((size_t)tn * BB + b) * GG + g];

            const float4* hq = (const float4*)&hbuf[cur][ty][0];

            // packed dot: 12 pairs per gate (48 pk_fma) + tail k=24 (4 fmac)
            f32x2 aA = {0.f,0.f}, aB = {0.f,0.f}, aC = {0.f,0.f}, aD = {0.f,0.f};
            #pragma unroll
            for (int i = 0; i < 6; ++i) {
                const float4 h4 = hq[i];
                const f32x2 h01 = {h4.x, h4.y};
                const f32x2 h23 = {h4.z, h4.w};
                PKFMA(aA, Wp[0][2*i  ], h01); PKFMA(aA, Wp[0][2*i+1], h23);
                PKFMA(aB, Wp[1][2*i  ], h01); PKFMA(aB, Wp[1][2*i+1], h23);
                PKFMA(aC, Wp[2][2*i  ], h01); PKFMA(aC, Wp[2][2*i+1], h23);
                PKFMA(aD, Wp[3][2*i  ], h01); PKFMA(aD, Wp[3][2*i+1], h23);
            }
            const float hl = hq[6].x;   // k = 24 of the quarter
            float pA = aA.x + aA.y + Wt[0] * hl;
            float pB = aB.x + aB.y + Wt[1] * hl;
            float pC = aC.x + aC.y + Wt[2] * hl;
            float pD = aD.x + aD.y + Wt[3] * hl;

            // cross-quad combine: lane j gets gate-j partials from j-1,j-2,j-3
            float tot = pA + dppf<DPP_ROT1>(pB) + dppf<DPP_ROT2>(pC)
                           + dppf<DPP_ROT3>(pD) + ext;

            // activation by own role (ty==2 is the g-gate -> tanh)
            const bool isG = (ty == 2);
            float v = isG ? 2.f * tot : tot;
            float s = frcp(1.f + fexp2(-LOG2E * v));
            if (isG) s = 2.f * s - 1.f;

            // gather the other three activated gates
            float B0 = dppf<DPP_XOR1>(s), C0 = dppf<DPP_XOR2>(s), D0 = dppf<DPP_XOR3>(s);

            if (ty == 0) {   // s=sig(i), B0=sig(f), C0=tanh(g), D0=sig(o)
                c = B0 * c + s * C0;
                float th = 2.f * frcp(1.f + fexp2(-2.f * LOG2E * c)) - 1.f;
                float hv = D0 * th;
                hbuf[nxt][q_w][i_w] = hv;
                if (LK < 2) hs[((size_t)b * TT + t) * HH + u] = hv;
            }
        }
        bar_lds();   // h(t) visible; orders hbuf[cur] reuse at t+1
    }

    // head: final h is in hbuf[0] (t=255 wrote nxt=0)
    if (LK == 2 && tid < 64) {
        const int lane = tid;
        float p = hbuf[0][lane / 25][lane % 25] * head_w[lane];
        if (lane < 36) {
            const int k2 = 64 + lane;
            p += hbuf[0][k2 / 25][k2 % 25] * head_w[k2];
        }
        #pragma unroll
        for (int off = 32; off; off >>= 1) p += __shfl_down(p, off);
        if (lane == 0) out[b] = p + head_b[0];
    }
}

// ============================ x-projection GEMM (MFMA) =======================
// (unchanged from R15 — ~130 us each, absmax clean)
__global__ void __launch_bounds__(512, 1)
gemm_pre(const float* __restrict__ hs,     // [B][T][100]
         const float* __restrict__ Wih,    // [400][100]
         const float* __restrict__ bih,    // [400]
         const float* __restrict__ bhh,    // [400]
         float* __restrict__ pre)          // [T*B][400]
{
    extern __shared__ short Ws[];          // [2][208][128] shorts (hi, lo)

    const int tid = threadIdx.x;
    const int l   = tid & 63, w = tid >> 6;   // lane, wave(=M-tile)
    const int lr  = l & 15, lg = l >> 4;
    const int row0   = blockIdx.x * 128;      // same t (512%128==0)
    const int t      = row0 >> 9;
    const int b_base = row0 & 511;
    const int gbase  = blockIdx.y * 200;

    {
        int* wz = (int*)Ws;
        for (int i = tid; i < 26624; i += 512) wz[i] = 0;
    }
    __syncthreads();

    for (int L = tid; L < 20000; L += 512) {
        const int g = L / 100, k = L % 100;
        const float v = Wih[(size_t)(gbase + g) * HH + k];
        const unsigned hh = bf16rne(v);
        const float rem = v - __uint_as_float(hh << 16);
        const unsigned lo = bf16rne(rem);
        const int kp = (((k >> 3) ^ (g & 15)) << 3) | (k & 7);   // slot swizzle
        Ws[(size_t)g * 128 + kp]          = (short)hh;
        Ws[(size_t)(208 + g) * 128 + kp]  = (short)lo;
    }

    bf16x8 Ahi[4], Alo[4];
    {
        const float* hrow = hs + ((size_t)(b_base + 16 * w + lr) * TT + t) * HH;
        #pragma unroll
        for (int kt = 0; kt < 4; ++kt) {
            const int k0 = 32 * kt + 8 * lg;
            float4 v0 = {0.f,0.f,0.f,0.f}, v1 = {0.f,0.f,0.f,0.f};
            if (k0     <= 96) v0 = *(const float4*)(hrow + k0);
            if (k0 + 4 <= 96) v1 = *(const float4*)(hrow + k0 + 4);
            const float e[8] = {v0.x,v0.y,v0.z,v0.w,v1.x,v1.y,v1.z,v1.w};
            short sh[8], sl[8];
            #pragma unroll
            for (int i = 0; i < 8; ++i) {
                const unsigned hh = bf16rne(e[i]);
                const float rem = e[i] - __uint_as_float(hh << 16);
                sh[i] = (short)hh;
                sl[i] = (short)bf16rne(rem);
            }
            Ahi[kt] = (bf16x8){sh[0],sh[1],sh[2],sh[3],sh[4],sh[5],sh[6],sh[7]};
            Alo[kt] = (bf16x8){sl[0],sl[1],sl[2],sl[3],sl[4],sl[5],sl[6],sl[7]};
        }
    }
    __syncthreads();   // W staged

    #pragma unroll
    for (int n = 0; n < 13; ++n) {
        const int gp = 16 * n + lr;               // W row in this block's slice
        bf16x8 Bhi[4], Blo[4];
        #pragma unroll
        for (int kt = 0; kt < 4; ++kt) {
            const int slot = (4 * kt + lg) ^ (gp & 15);
            Bhi[kt] = *(const bf16x8*)&Ws[(size_t)gp * 128 + slot * 8];
            Blo[kt] = *(const bf16x8*)&Ws[(size_t)(208 + gp) * 128 + slot * 8];
        }
        f32x4 acc = {0.f, 0.f, 0.f, 0.f};
        #pragma unroll
        for (int kt = 0; kt < 4; ++kt) {
            acc = __builtin_amdgcn_mfma_f32_16x16x32_bf16(Ahi[kt], Bhi[kt], acc, 0, 0, 0);
            acc = __builtin_amdgcn_mfma_f32_16x16x32_bf16(Alo[kt], Bhi[kt], acc, 0, 0, 0);
            acc = __builtin_amdgcn_mfma_f32_16x16x32_bf16(Ahi[kt], Blo[kt], acc, 0, 0, 0);
        }
        const int gcol = gbase + 16 * n + lr;
        if (gcol < GG) {
            const float bsum = bih[gcol] + bhh[gcol];
            #pragma unroll
            for (int r = 0; r < 4; ++r) {
                const size_t row = (size_t)row0 + 16 * w + 4 * lg + r;
                pre[row * GG + gcol] = acc[r] + bsum;
            }
        }
    }
}

// =============================================================================
extern "C" void kernel_launch(void* const* d_in, const int* in_sizes, int n_in,
                              void* d_out, int out_size, void* d_ws, size_t ws_size,
                              hipStream_t stream) {
    const float* x         = (const float*)d_in[0];
    const float* W_ih0     = (const float*)d_in[1];
    const float* W_ih_rest = (const float*)d_in[2];
    const float* W_hh      = (const float*)d_in[3];
    const float* b_ih      = (const float*)d_in[4];
    const float* b_hh      = (const float*)d_in[5];
    const float* head_w    = (const float*)d_in[6];
    const float* head_b    = (const float*)d_in[7];
    float* out = (float*)d_out;

    const size_t HS_BYTES = (size_t)BB * TT * HH * 4;   // 52.4 MB
    float* hs  = (float*)d_ws;
    float* pre = (float*)((char*)d_ws + HS_BYTES);      // 209.7 MB

    const int gemm_lds = 2 * 208 * 128 * 2;             // 106,496 B
    hipFuncSetAttribute((const void*)gemm_pre,
                        hipFuncAttributeMaxDynamicSharedMemorySize, gemm_lds);
    dim3 ggrid(1024, 2);

    lstm_recur<0><<<512, 448, 0, stream>>>(
        x, nullptr, W_hh, W_ih0, b_ih, b_hh, head_w, head_b, hs, out);

    gemm_pre<<<ggrid, 512, gemm_lds, stream>>>(hs, W_ih_rest, b_ih + GG, b_hh + GG, pre);
    lstm_recur<1><<<512, 448, 0, stream>>>(
        nullptr, pre, W_hh + 40000, nullptr, nullptr, nullptr, head_w, head_b, hs, out);

    gemm_pre<<<ggrid, 512, gemm_lds, stream>>>(hs, W_ih_rest + 40000, b_ih + 2*GG, b_hh + 2*GG, pre);
    lstm_recur<2><<<512, 448, 0, stream>>>(
        nullptr, pre, W_hh + 80000, nullptr, nullptr, nullptr, head_w, head_b, hs, out);
}

// Round 18
// 758.424 us; speedup vs baseline: 1.4619x; 1.4619x over previous
//
#include <hip/hip_runtime.h>
#include <math.h>

#define TT 256
#define HH 100
#define GG 400
#define BB 512

typedef float  f32x4  __attribute__((ext_vector_type(4)));
typedef short  bf16x8 __attribute__((ext_vector_type(8)));

// ---- DPP quad-perm helpers (4-lane groups; VALU pipe) ----------------------
#define DPP_ROT1 147   // dest l <- src (l-1)&3 : perm [3,0,1,2]
#define DPP_ROT2 78    // dest l <- src (l-2)&3 : perm [2,3,0,1]
#define DPP_ROT3 57    // dest l <- src (l-3)&3 : perm [1,2,3,0]
#define DPP_XOR1 177   // perm [1,0,3,2]
#define DPP_XOR2 78    // perm [2,3,0,1]
#define DPP_XOR3 27    // perm [3,2,1,0]

template<int CTRL>
__device__ __forceinline__ float dppf(float v) {
    int i = __float_as_int(v);
    int r = __builtin_amdgcn_update_dpp(i, i, CTRL, 0xf, 0xf, false);
    return __int_as_float(r);
}

// raw transcendental ops (validated: absmax <= 6.1e-5 since R8)
__device__ __forceinline__ float fexp2(float x) {
    float r; asm("v_exp_f32 %0, %1" : "=v"(r) : "v"(x)); return r;
}
__device__ __forceinline__ float frcp(float x) {
    float r; asm("v_rcp_f32 %0, %1" : "=v"(r) : "v"(x)); return r;
}
#define LOG2E 1.44269504088896f

// bf16 round-to-nearest-even of fp32 (returns 16-bit pattern)
__device__ __forceinline__ unsigned bf16rne(float x) {
    unsigned b = __float_as_uint(x);
    return (b + 0x7FFFu + ((b >> 16) & 1u)) >> 16;
}

// LDS-drain-only barrier: keeps global loads/stores in flight
__device__ __forceinline__ void bar_lds() {
    asm volatile("s_waitcnt lgkmcnt(0)" ::: "memory");
    __builtin_amdgcn_s_barrier();
    asm volatile("" ::: "memory");
}

// ============================ recurrence kernel ==============================
// R8/R15 structure: 512 blocks x 448 threads, 1 batch row/block, 2 blocks/CU;
// lb(448,3). Thread (u=tid>>2, ty=tid&3): k-quarter [25ty,25ty+25) partials
// for gates {((ty+d)&3)*100+u}; DPP-rotate combine (R4-verified).
// h double-buffered in LDS [2][4][28]. Weights as statically-indexed f32x4
// quads.
template<int LK>
__global__ void __launch_bounds__(448, 3)
lstm_recur(const float* __restrict__ x,        // [B][T][2]   (LK==0)
           const float* __restrict__ pre,      // [T*B][400]  (LK>=1, bias folded)
           const float* __restrict__ Whh,      // [400][100]
           const float* __restrict__ Wih0,     // [400][2]    (LK==0)
           const float* __restrict__ bih,      // [400]       (LK==0)
           const float* __restrict__ bhh,      // [400]       (LK==0)
           const float* __restrict__ head_w,   // [100]
           const float* __restrict__ head_b,   // [1]
           float* __restrict__ hs,             // [B][T][100] (LK<2 out)
           float* __restrict__ out)            // [B]         (LK==2 out)
{
    __shared__ float hbuf[2][4][28];   // [buf][quarter][25 used + 3 pad]

    const int tid = threadIdx.x;
    const int b   = blockIdx.x;        // one batch row per block
    const int u   = tid >> 2, ty = tid & 3;
    const int g   = ty * HH + u;       // own gate row
    const bool on = (tid < GG);

    // Wq4[d][q] = quad {W[4q..4q+3]} of Whh[((ty+d)&3)*100+u][25ty..25ty+24];
    // q=6 holds {W[24],0,0,0}.
    f32x4 Wq4[4][7];
    float w0a = 0.f, w0b = 0.f, bias = 0.f;
    if (on) {
        #pragma unroll
        for (int d = 0; d < 4; ++d) {
            const float* wrow = Whh + (((ty + d) & 3) * HH + u) * HH + 25 * ty;
            #pragma unroll
            for (int q = 0; q < 6; ++q)
                Wq4[d][q] = (f32x4){wrow[4*q], wrow[4*q+1], wrow[4*q+2], wrow[4*q+3]};
            Wq4[d][6] = (f32x4){wrow[24], 0.f, 0.f, 0.f};
        }
        if (LK == 0) {
            w0a = Wih0[2 * g]; w0b = Wih0[2 * g + 1];
            bias = bih[g] + bhh[g];
        }
    }
    if (tid < 224) (&hbuf[0][0][0])[tid] = 0.f;   // zero both bufs incl. pads
    float c = 0.f;                                // ty==0 lanes own unit u's cell
    const int q_w = u / 25, i_w = u % 25;         // writer position
    __syncthreads();

    // prefetch t=0 input
    float p0 = 0.f;
    float2 xa = {0.f, 0.f};
    if (on) {
        if (LK == 0) xa = *(const float2*)(x + (size_t)b * TT * 2);
        else         p0 = pre[((size_t)0 * BB + b) * GG + g];
    }

    for (int t = 0; t < TT; ++t) {
        const int cur = t & 1, nxt = cur ^ 1;
        if (on) {
            float ext;
            if (LK == 0) ext = bias + w0a * xa.x + w0b * xa.y;
            else         ext = p0;

            // prefetch t+1 (stays in flight across the raw barrier)
            const int tn = (t + 1 < TT) ? t + 1 : t;
            if (LK == 0) xa = *(const float2*)(x + ((size_t)b * TT + tn) * 2);
            else         p0 = pre[((size_t)tn * BB + b) * GG + g];

            const float4* hq = (const float4*)&hbuf[cur][ty][0];

            float pA = 0.f, pB = 0.f, pC = 0.f, pD = 0.f;
            #pragma unroll
            for (int i = 0; i < 6; ++i) {
                const float4 h4 = hq[i];
                pA += Wq4[0][i].x * h4.x; pB += Wq4[1][i].x * h4.x;
                pC += Wq4[2][i].x * h4.x; pD += Wq4[3][i].x * h4.x;
                pA += Wq4[0][i].y * h4.y; pB += Wq4[1][i].y * h4.y;
                pC += Wq4[2][i].y * h4.y; pD += Wq4[3][i].y * h4.y;
                pA += Wq4[0][i].z * h4.z; pB += Wq4[1][i].z * h4.z;
                pC += Wq4[2][i].z * h4.z; pD += Wq4[3][i].z * h4.z;
                pA += Wq4[0][i].w * h4.w; pB += Wq4[1][i].w * h4.w;
                pC += Wq4[2][i].w * h4.w; pD += Wq4[3][i].w * h4.w;
            }
            const float hl = hq[6].x;   // k = 24 of the quarter
            pA += Wq4[0][6].x * hl; pB += Wq4[1][6].x * hl;
            pC += Wq4[2][6].x * hl; pD += Wq4[3][6].x * hl;

            // cross-quad combine: lane j gets gate-j partials from j-1,j-2,j-3
            float tot = pA + dppf<DPP_ROT1>(pB) + dppf<DPP_ROT2>(pC)
                           + dppf<DPP_ROT3>(pD) + ext;

            // activation by own role (ty==2 is the g-gate -> tanh)
            const bool isG = (ty == 2);
            float v = isG ? 2.f * tot : tot;
            float s = frcp(1.f + fexp2(-LOG2E * v));
            if (isG) s = 2.f * s - 1.f;

            // gather the other three activated gates
            float B0 = dppf<DPP_XOR1>(s), C0 = dppf<DPP_XOR2>(s), D0 = dppf<DPP_XOR3>(s);

            if (ty == 0) {   // s=sig(i), B0=sig(f), C0=tanh(g), D0=sig(o)
                c = B0 * c + s * C0;
                float th = 2.f * frcp(1.f + fexp2(-2.f * LOG2E * c)) - 1.f;
                float hv = D0 * th;
                hbuf[nxt][q_w][i_w] = hv;
                if (LK < 2) hs[((size_t)b * TT + t) * HH + u] = hv;
            }
        }
        bar_lds();   // h(t) visible; orders hbuf[cur] reuse at t+1
    }

    // head: final h is in hbuf[0] (t=255 wrote nxt=0)
    if (LK == 2 && tid < 64) {
        const int lane = tid;
        float p = hbuf[0][lane / 25][lane % 25] * head_w[lane];
        if (lane < 36) {
            const int k2 = 64 + lane;
            p += hbuf[0][k2 / 25][k2 % 25] * head_w[k2];
        }
        #pragma unroll
        for (int off = 32; off; off >>= 1) p += __shfl_down(p, off);
        if (lane == 0) out[b] = p + head_b[0];
    }
}

// ====================== x-projection GEMM (MFMA, persistent) =================
// MFMA bf16x3, persistent: grid (128,2) = 1 block/CU; W staged+split to LDS
// ONCE, 8 row-chunks of 128 reuse it.
// BUGFIX (R17 fail, latent since R15): N-tile 12 is a HALF tile — lanes with
// gp >= 200 hit the zeroed pad rows and previously STORED bias-only values to
// gates 200-207, racing with the other y-slice's correct writes. Store guard
// is now gp < 200 (exactly the owned 200-gate slice).
__global__ void __launch_bounds__(512, 1)
gemm_pre(const float* __restrict__ hs,     // [B][T][100]
         const float* __restrict__ Wih,    // [400][100]
         const float* __restrict__ bih,    // [400]
         const float* __restrict__ bhh,    // [400]
         float* __restrict__ pre)          // [T*B][400]
{
    extern __shared__ short Ws[];          // [2][208][128] shorts (hi, lo)

    const int tid = threadIdx.x;
    const int l   = tid & 63, w = tid >> 6;   // lane, wave(=M-tile)
    const int lr  = l & 15, lg = l >> 4;
    const int gbase = blockIdx.y * 200;

    // ---- zero W LDS (covers k>=100 and gate rows 200-207 pads) ----
    {
        int* wz = (int*)Ws;
        for (int i = tid; i < 26624; i += 512) wz[i] = 0;
    }
    __syncthreads();

    // ---- stage + split W once: 200 gates x 100 k ----
    for (int L = tid; L < 20000; L += 512) {
        const int g = L / 100, k = L % 100;
        const float v = Wih[(size_t)(gbase + g) * HH + k];
        const unsigned hh = bf16rne(v);
        const float rem = v - __uint_as_float(hh << 16);
        const unsigned lo = bf16rne(rem);
        const int kp = (((k >> 3) ^ (g & 15)) << 3) | (k & 7);   // slot swizzle
        Ws[(size_t)g * 128 + kp]          = (short)hh;
        Ws[(size_t)(208 + g) * 128 + kp]  = (short)lo;
    }
    __syncthreads();   // W staged for the whole kernel

    // ---- 8 row-chunks of 128 rows ----
    for (int c = 0; c < 8; ++c) {
        const int row0   = blockIdx.x * 1024 + c * 128;   // same t per chunk
        const int t      = row0 >> 9;
        const int b_base = row0 & 511;

        // A-frags in registers: row b_base+16w+lr, hi/lo split
        bf16x8 Ahi[4], Alo[4];
        {
            const float* hrow = hs + ((size_t)(b_base + 16 * w + lr) * TT + t) * HH;
            #pragma unroll
            for (int kt = 0; kt < 4; ++kt) {
                const int k0 = 32 * kt + 8 * lg;
                float4 v0 = {0.f,0.f,0.f,0.f}, v1 = {0.f,0.f,0.f,0.f};
                if (k0     <= 96) v0 = *(const float4*)(hrow + k0);
                if (k0 + 4 <= 96) v1 = *(const float4*)(hrow + k0 + 4);
                const float e[8] = {v0.x,v0.y,v0.z,v0.w,v1.x,v1.y,v1.z,v1.w};
                short sh[8], sl[8];
                #pragma unroll
                for (int i = 0; i < 8; ++i) {
                    const unsigned hh = bf16rne(e[i]);
                    const float rem = e[i] - __uint_as_float(hh << 16);
                    sh[i] = (short)hh;
                    sl[i] = (short)bf16rne(rem);
                }
                Ahi[kt] = (bf16x8){sh[0],sh[1],sh[2],sh[3],sh[4],sh[5],sh[6],sh[7]};
                Alo[kt] = (bf16x8){sl[0],sl[1],sl[2],sl[3],sl[4],sl[5],sl[6],sl[7]};
            }
        }

        // N-tile loop: 13 tiles of 16 gates (tile 12 is a half tile)
        #pragma unroll
        for (int n = 0; n < 13; ++n) {
            const int gp = 16 * n + lr;
            bf16x8 Bhi[4], Blo[4];
            #pragma unroll
            for (int kt = 0; kt < 4; ++kt) {
                const int slot = (4 * kt + lg) ^ (gp & 15);
                Bhi[kt] = *(const bf16x8*)&Ws[(size_t)gp * 128 + slot * 8];
                Blo[kt] = *(const bf16x8*)&Ws[(size_t)(208 + gp) * 128 + slot * 8];
            }
            f32x4 acc = {0.f, 0.f, 0.f, 0.f};
            #pragma unroll
            for (int kt = 0; kt < 4; ++kt) {
                acc = __builtin_amdgcn_mfma_f32_16x16x32_bf16(Ahi[kt], Bhi[kt], acc, 0, 0, 0);
                acc = __builtin_amdgcn_mfma_f32_16x16x32_bf16(Alo[kt], Bhi[kt], acc, 0, 0, 0);
                acc = __builtin_amdgcn_mfma_f32_16x16x32_bf16(Ahi[kt], Blo[kt], acc, 0, 0, 0);
            }
            if (gp < 200) {                       // own-slice stores only
                const int gcol = gbase + gp;
                const float bsum = bih[gcol] + bhh[gcol];
                #pragma unroll
                for (int r = 0; r < 4; ++r) {
                    const size_t row = (size_t)row0 + 16 * w + 4 * lg + r;
                    pre[row * GG + gcol] = acc[r] + bsum;
                }
            }
        }
    }
}

// =============================================================================
extern "C" void kernel_launch(void* const* d_in, const int* in_sizes, int n_in,
                              void* d_out, int out_size, void* d_ws, size_t ws_size,
                              hipStream_t stream) {
    const float* x         = (const float*)d_in[0];
    const float* W_ih0     = (const float*)d_in[1];
    const float* W_ih_rest = (const float*)d_in[2];
    const float* W_hh      = (const float*)d_in[3];
    const float* b_ih      = (const float*)d_in[4];
    const float* b_hh      = (const float*)d_in[5];
    const float* head_w    = (const float*)d_in[6];
    const float* head_b    = (const float*)d_in[7];
    float* out = (float*)d_out;

    const size_t HS_BYTES = (size_t)BB * TT * HH * 4;   // 52.4 MB
    float* hs  = (float*)d_ws;
    float* pre = (float*)((char*)d_ws + HS_BYTES);      // 209.7 MB

    const int gemm_lds = 2 * 208 * 128 * 2;             // 106,496 B
    hipFuncSetAttribute((const void*)gemm_pre,
                        hipFuncAttributeMaxDynamicSharedMemorySize, gemm_lds);
    dim3 ggrid(128, 2);

    lstm_recur<0><<<512, 448, 0, stream>>>(
        x, nullptr, W_hh, W_ih0, b_ih, b_hh, head_w, head_b, hs, out);

    gemm_pre<<<ggrid, 512, gemm_lds, stream>>>(hs, W_ih_rest, b_ih + GG, b_hh + GG, pre);
    lstm_recur<1><<<512, 448, 0, stream>>>(
        nullptr, pre, W_hh + 40000, nullptr, nullptr, nullptr, head_w, head_b, hs, out);

    gemm_pre<<<ggrid, 512, gemm_lds, stream>>>(hs, W_ih_rest + 40000, b_ih + 2*GG, b_hh + 2*GG, pre);
    lstm_recur<2><<<512, 448, 0, stream>>>(
        nullptr, pre, W_hh + 80000, nullptr, nullptr, nullptr, head_w, head_b, hs, out);
}

// Round 19
// 741.304 us; speedup vs baseline: 1.4957x; 1.0231x over previous
//
#include <hip/hip_runtime.h>
#include <math.h>

#define TT 256
#define HH 100
#define GG 400
#define BB 512

typedef float  f32x4  __attribute__((ext_vector_type(4)));
typedef short  bf16x8 __attribute__((ext_vector_type(8)));

// ---- DPP quad-perm helpers (4-lane groups; VALU pipe) ----------------------
#define DPP_ROT1 147   // dest l <- src (l-1)&3 : perm [3,0,1,2]
#define DPP_ROT2 78    // dest l <- src (l-2)&3 : perm [2,3,0,1]
#define DPP_ROT3 57    // dest l <- src (l-3)&3 : perm [1,2,3,0]
#define DPP_XOR1 177   // perm [1,0,3,2]
#define DPP_XOR2 78    // perm [2,3,0,1]
#define DPP_XOR3 27    // perm [3,2,1,0]

template<int CTRL>
__device__ __forceinline__ float dppf(float v) {
    int i = __float_as_int(v);
    int r = __builtin_amdgcn_update_dpp(i, i, CTRL, 0xf, 0xf, false);
    return __int_as_float(r);
}

// raw transcendental ops (validated: absmax <= 6.1e-5 since R8)
__device__ __forceinline__ float fexp2(float x) {
    float r; asm("v_exp_f32 %0, %1" : "=v"(r) : "v"(x)); return r;
}
__device__ __forceinline__ float frcp(float x) {
    float r; asm("v_rcp_f32 %0, %1" : "=v"(r) : "v"(x)); return r;
}
#define LOG2E 1.44269504088896f

// bf16 round-to-nearest-even of fp32 (returns 16-bit pattern)
__device__ __forceinline__ unsigned bf16rne(float x) {
    unsigned b = __float_as_uint(x);
    return (b + 0x7FFFu + ((b >> 16) & 1u)) >> 16;
}

// LDS-drain-only barrier: keeps global loads/stores in flight
__device__ __forceinline__ void bar_lds() {
    asm volatile("s_waitcnt lgkmcnt(0)" ::: "memory");
    __builtin_amdgcn_s_barrier();
    asm volatile("" ::: "memory");
}

// ============================ recurrence kernel ==============================
// R8 structure, but lb(448,2): VGPR cap 256. Every recur compile at
// lb(448,3) (cap 170) AGPR-banked the 100-float Wq (VGPR_Count 64-88,
// ~2.5x VALU-issue inflation, R8-R18). The only CLEAN 100-float-array
// compiles ever observed were both at cap 256 (R2 gemm lb(512,2) VGPR=108;
// R10 gemm lb(448,2) VGPR=128, no scratch). lb(448,2) still permits
// 2 blocks/CU (14 waves) if actual usage <= 146.
// Thread (u=tid>>2, ty=tid&3): k-quarter [25ty,25ty+25) partials for gates
// {((ty+d)&3)*100+u}; DPP-rotate combine (R4-verified). h dbuf LDS [2][4][28].
template<int LK>
__global__ void __launch_bounds__(448, 2)
lstm_recur(const float* __restrict__ x,        // [B][T][2]   (LK==0)
           const float* __restrict__ pre,      // [T*B][400]  (LK>=1, bias folded)
           const float* __restrict__ Whh,      // [400][100]
           const float* __restrict__ Wih0,     // [400][2]    (LK==0)
           const float* __restrict__ bih,      // [400]       (LK==0)
           const float* __restrict__ bhh,      // [400]       (LK==0)
           const float* __restrict__ head_w,   // [100]
           const float* __restrict__ head_b,   // [1]
           float* __restrict__ hs,             // [B][T][100] (LK<2 out)
           float* __restrict__ out)            // [B]         (LK==2 out)
{
    __shared__ float hbuf[2][4][28];   // [buf][quarter][25 used + 3 pad]

    const int tid = threadIdx.x;
    const int b   = blockIdx.x;        // one batch row per block
    const int u   = tid >> 2, ty = tid & 3;
    const int g   = ty * HH + u;       // own gate row
    const bool on = (tid < GG);

    // Wq[d][k] = Whh[((ty+d)&3)*100 + u][25*ty + k]
    float Wq[4][25];
    float w0a = 0.f, w0b = 0.f, bias = 0.f;
    if (on) {
        #pragma unroll
        for (int d = 0; d < 4; ++d) {
            const float* wrow = Whh + (((ty + d) & 3) * HH + u) * HH + 25 * ty;
            #pragma unroll
            for (int k = 0; k < 25; ++k) Wq[d][k] = wrow[k];
        }
        if (LK == 0) {
            w0a = Wih0[2 * g]; w0b = Wih0[2 * g + 1];
            bias = bih[g] + bhh[g];
        }
    }
    if (tid < 224) (&hbuf[0][0][0])[tid] = 0.f;   // zero both bufs incl. pads
    float c = 0.f;                                // ty==0 lanes own unit u's cell
    const int q_w = u / 25, i_w = u % 25;         // writer position
    __syncthreads();

    // prefetch t=0 input
    float p0 = 0.f;
    float2 xa = {0.f, 0.f};
    if (on) {
        if (LK == 0) xa = *(const float2*)(x + (size_t)b * TT * 2);
        else         p0 = pre[((size_t)0 * BB + b) * GG + g];
    }

    for (int t = 0; t < TT; ++t) {
        const int cur = t & 1, nxt = cur ^ 1;
        if (on) {
            float ext;
            if (LK == 0) ext = bias + w0a * xa.x + w0b * xa.y;
            else         ext = p0;

            // prefetch t+1 (stays in flight across the raw barrier)
            const int tn = (t + 1 < TT) ? t + 1 : t;
            if (LK == 0) xa = *(const float2*)(x + ((size_t)b * TT + tn) * 2);
            else         p0 = pre[((size_t)tn * BB + b) * GG + g];

            const float4* hq = (const float4*)&hbuf[cur][ty][0];

            float pA = 0.f, pB = 0.f, pC = 0.f, pD = 0.f;
            #pragma unroll
            for (int i = 0; i < 6; ++i) {
                const float4 h4 = hq[i];
                pA += Wq[0][4*i+0] * h4.x; pB += Wq[1][4*i+0] * h4.x;
                pC += Wq[2][4*i+0] * h4.x; pD += Wq[3][4*i+0] * h4.x;
                pA += Wq[0][4*i+1] * h4.y; pB += Wq[1][4*i+1] * h4.y;
                pC += Wq[2][4*i+1] * h4.y; pD += Wq[3][4*i+1] * h4.y;
                pA += Wq[0][4*i+2] * h4.z; pB += Wq[1][4*i+2] * h4.z;
                pC += Wq[2][4*i+2] * h4.z; pD += Wq[3][4*i+2] * h4.z;
                pA += Wq[0][4*i+3] * h4.w; pB += Wq[1][4*i+3] * h4.w;
                pC += Wq[2][4*i+3] * h4.w; pD += Wq[3][4*i+3] * h4.w;
            }
            const float hl = hq[6].x;   // k = 24 of the quarter
            pA += Wq[0][24] * hl; pB += Wq[1][24] * hl;
            pC += Wq[2][24] * hl; pD += Wq[3][24] * hl;

            // cross-quad combine: lane j gets gate-j partials from j-1,j-2,j-3
            float tot = pA + dppf<DPP_ROT1>(pB) + dppf<DPP_ROT2>(pC)
                           + dppf<DPP_ROT3>(pD) + ext;

            // activation by own role (ty==2 is the g-gate -> tanh)
            const bool isG = (ty == 2);
            float v = isG ? 2.f * tot : tot;
            float s = frcp(1.f + fexp2(-LOG2E * v));
            if (isG) s = 2.f * s - 1.f;

            // gather the other three activated gates
            float B0 = dppf<DPP_XOR1>(s), C0 = dppf<DPP_XOR2>(s), D0 = dppf<DPP_XOR3>(s);

            if (ty == 0) {   // s=sig(i), B0=sig(f), C0=tanh(g), D0=sig(o)
                c = B0 * c + s * C0;
                float th = 2.f * frcp(1.f + fexp2(-2.f * LOG2E * c)) - 1.f;
                float hv = D0 * th;
                hbuf[nxt][q_w][i_w] = hv;
                if (LK < 2) hs[((size_t)b * TT + t) * HH + u] = hv;
            }
        }
        bar_lds();   // h(t) visible; orders hbuf[cur] reuse at t+1
    }

    // head: final h is in hbuf[0] (t=255 wrote nxt=0)
    if (LK == 2 && tid < 64) {
        const int lane = tid;
        float p = hbuf[0][lane / 25][lane % 25] * head_w[lane];
        if (lane < 36) {
            const int k2 = 64 + lane;
            p += hbuf[0][k2 / 25][k2 % 25] * head_w[k2];
        }
        #pragma unroll
        for (int off = 32; off; off >>= 1) p += __shfl_down(p, off);
        if (lane == 0) out[b] = p + head_b[0];
    }
}

// ====================== x-projection GEMM (MFMA, persistent) =================
// (unchanged from R18 — near-free: pre stays in L2/L3) MFMA bf16x3,
// persistent grid (128,2) = 1 block/CU; W staged+split to LDS ONCE,
// 8 row-chunks of 128 reuse it. Store guard gp<200 (R18 race fix).
__global__ void __launch_bounds__(512, 1)
gemm_pre(const float* __restrict__ hs,     // [B][T][100]
         const float* __restrict__ Wih,    // [400][100]
         const float* __restrict__ bih,    // [400]
         const float* __restrict__ bhh,    // [400]
         float* __restrict__ pre)          // [T*B][400]
{
    extern __shared__ short Ws[];          // [2][208][128] shorts (hi, lo)

    const int tid = threadIdx.x;
    const int l   = tid & 63, w = tid >> 6;   // lane, wave(=M-tile)
    const int lr  = l & 15, lg = l >> 4;
    const int gbase = blockIdx.y * 200;

    // ---- zero W LDS (covers k>=100 and gate rows 200-207 pads) ----
    {
        int* wz = (int*)Ws;
        for (int i = tid; i < 26624; i += 512) wz[i] = 0;
    }
    __syncthreads();

    // ---- stage + split W once: 200 gates x 100 k ----
    for (int L = tid; L < 20000; L += 512) {
        const int g = L / 100, k = L % 100;
        const float v = Wih[(size_t)(gbase + g) * HH + k];
        const unsigned hh = bf16rne(v);
        const float rem = v - __uint_as_float(hh << 16);
        const unsigned lo = bf16rne(rem);
        const int kp = (((k >> 3) ^ (g & 15)) << 3) | (k & 7);   // slot swizzle
        Ws[(size_t)g * 128 + kp]          = (short)hh;
        Ws[(size_t)(208 + g) * 128 + kp]  = (short)lo;
    }
    __syncthreads();   // W staged for the whole kernel

    // ---- 8 row-chunks of 128 rows ----
    for (int c = 0; c < 8; ++c) {
        const int row0   = blockIdx.x * 1024 + c * 128;   // same t per chunk
        const int t      = row0 >> 9;
        const int b_base = row0 & 511;

        // A-frags in registers: row b_base+16w+lr, hi/lo split
        bf16x8 Ahi[4], Alo[4];
        {
            const float* hrow = hs + ((size_t)(b_base + 16 * w + lr) * TT + t) * HH;
            #pragma unroll
            for (int kt = 0; kt < 4; ++kt) {
                const int k0 = 32 * kt + 8 * lg;
                float4 v0 = {0.f,0.f,0.f,0.f}, v1 = {0.f,0.f,0.f,0.f};
                if (k0     <= 96) v0 = *(const float4*)(hrow + k0);
                if (k0 + 4 <= 96) v1 = *(const float4*)(hrow + k0 + 4);
                const float e[8] = {v0.x,v0.y,v0.z,v0.w,v1.x,v1.y,v1.z,v1.w};
                short sh[8], sl[8];
                #pragma unroll
                for (int i = 0; i < 8; ++i) {
                    const unsigned hh = bf16rne(e[i]);
                    const float rem = e[i] - __uint_as_float(hh << 16);
                    sh[i] = (short)hh;
                    sl[i] = (short)bf16rne(rem);
                }
                Ahi[kt] = (bf16x8){sh[0],sh[1],sh[2],sh[3],sh[4],sh[5],sh[6],sh[7]};
                Alo[kt] = (bf16x8){sl[0],sl[1],sl[2],sl[3],sl[4],sl[5],sl[6],sl[7]};
            }
        }

        // N-tile loop: 13 tiles of 16 gates (tile 12 is a half tile)
        #pragma unroll
        for (int n = 0; n < 13; ++n) {
            const int gp = 16 * n + lr;
            bf16x8 Bhi[4], Blo[4];
            #pragma unroll
            for (int kt = 0; kt < 4; ++kt) {
                const int slot = (4 * kt + lg) ^ (gp & 15);
                Bhi[kt] = *(const bf16x8*)&Ws[(size_t)gp * 128 + slot * 8];
                Blo[kt] = *(const bf16x8*)&Ws[(size_t)(208 + gp) * 128 + slot * 8];
            }
            f32x4 acc = {0.f, 0.f, 0.f, 0.f};
            #pragma unroll
            for (int kt = 0; kt < 4; ++kt) {
                acc = __builtin_amdgcn_mfma_f32_16x16x32_bf16(Ahi[kt], Bhi[kt], acc, 0, 0, 0);
                acc = __builtin_amdgcn_mfma_f32_16x16x32_bf16(Alo[kt], Bhi[kt], acc, 0, 0, 0);
                acc = __builtin_amdgcn_mfma_f32_16x16x32_bf16(Ahi[kt], Blo[kt], acc, 0, 0, 0);
            }
            if (gp < 200) {                       // own-slice stores only
                const int gcol = gbase + gp;
                const float bsum = bih[gcol] + bhh[gcol];
                #pragma unroll
                for (int r = 0; r < 4; ++r) {
                    const size_t row = (size_t)row0 + 16 * w + 4 * lg + r;
                    pre[row * GG + gcol] = acc[r] + bsum;
                }
            }
        }
    }
}

// =============================================================================
extern "C" void kernel_launch(void* const* d_in, const int* in_sizes, int n_in,
                              void* d_out, int out_size, void* d_ws, size_t ws_size,
                              hipStream_t stream) {
    const float* x         = (const float*)d_in[0];
    const float* W_ih0     = (const float*)d_in[1];
    const float* W_ih_rest = (const float*)d_in[2];
    const float* W_hh      = (const float*)d_in[3];
    const float* b_ih      = (const float*)d_in[4];
    const float* b_hh      = (const float*)d_in[5];
    const float* head_w    = (const float*)d_in[6];
    const float* head_b    = (const float*)d_in[7];
    float* out = (float*)d_out;

    const size_t HS_BYTES = (size_t)BB * TT * HH * 4;   // 52.4 MB
    float* hs  = (float*)d_ws;
    float* pre = (float*)((char*)d_ws + HS_BYTES);      // 209.7 MB

    const int gemm_lds = 2 * 208 * 128 * 2;             // 106,496 B
    hipFuncSetAttribute((const void*)gemm_pre,
                        hipFuncAttributeMaxDynamicSharedMemorySize, gemm_lds);
    dim3 ggrid(128, 2);

    lstm_recur<0><<<512, 448, 0, stream>>>(
        x, nullptr, W_hh, W_ih0, b_ih, b_hh, head_w, head_b, hs, out);

    gemm_pre<<<ggrid, 512, gemm_lds, stream>>>(hs, W_ih_rest, b_ih + GG, b_hh + GG, pre);
    lstm_recur<1><<<512, 448, 0, stream>>>(
        nullptr, pre, W_hh + 40000, nullptr, nullptr, nullptr, head_w, head_b, hs, out);

    gemm_pre<<<ggrid, 512, gemm_lds, stream>>>(hs, W_ih_rest + 40000, b_ih + 2*GG, b_hh + 2*GG, pre);
    lstm_recur<2><<<512, 448, 0, stream>>>(
        nullptr, pre, W_hh + 80000, nullptr, nullptr, nullptr, head_w, head_b, hs, out);
}